// Round 1
// baseline (3720.618 us; speedup 1.0000x reference)
//
#include <hip/hip_runtime.h>
#include <hip/hip_bf16.h>
#include <cstddef>

#define NN 100000
#define EE 3200000
#define EPSB 1e-5f

// ---------------------------------------------------------------- CSR build

__global__ void k_hist(const int* __restrict__ dst, int* __restrict__ degcnt) {
    int e = blockIdx.x * blockDim.x + threadIdx.x;
    if (e < EE) atomicAdd(&degcnt[dst[e]], 1);
}

__global__ void k_deg(const int* __restrict__ degcnt, float* __restrict__ dis,
                      float* __restrict__ di) {
    int i = blockIdx.x * blockDim.x + threadIdx.x;
    if (i < NN) {
        float d = (float)degcnt[i] + 1.0f;
        di[i]  = 1.0f / d;
        dis[i] = rsqrtf(d);
    }
}

__global__ void k_scan_block(const int* __restrict__ in, int* __restrict__ out,
                             int* __restrict__ blksum, int n) {
    __shared__ int s[1024];
    int i = blockIdx.x * 1024 + threadIdx.x;
    int v = (i < n) ? in[i] : 0;
    s[threadIdx.x] = v;
    __syncthreads();
    for (int off = 1; off < 1024; off <<= 1) {
        int t = (threadIdx.x >= off) ? s[threadIdx.x - off] : 0;
        __syncthreads();
        s[threadIdx.x] += t;
        __syncthreads();
    }
    if (i < n) out[i] = s[threadIdx.x] - v;  // exclusive
    if (threadIdx.x == 1023) blksum[blockIdx.x] = s[1023];
}

__global__ void k_scan_top(int* __restrict__ blksum, int nb) {
    if (threadIdx.x == 0) {
        int acc = 0;
        for (int b = 0; b < nb; b++) { int v = blksum[b]; blksum[b] = acc; acc += v; }
    }
}

__global__ void k_scan_add(int* __restrict__ out, const int* __restrict__ blksum, int n) {
    int i = blockIdx.x * 1024 + threadIdx.x;
    if (i < n) out[i] += blksum[blockIdx.x];
}

__global__ void k_fill(const int* __restrict__ src, const int* __restrict__ dst,
                       const int* __restrict__ rowptr, int* __restrict__ cursor,
                       int* __restrict__ col, float* __restrict__ val,
                       const float* __restrict__ dis) {
    int e = blockIdx.x * blockDim.x + threadIdx.x;
    if (e < EE) {
        int d = dst[e], s = src[e];
        int pos = rowptr[d] + atomicAdd(&cursor[d], 1);
        col[pos] = s;
        val[pos] = dis[s];
    }
}

// ---------------------------------------------------------------- GEMM (fp32)
// C[M,Nc] = A[M,K] @ B[K,Nc] (+ bias). BM=BN=64, BK=16, 256 thr, 4x4/thread.

__global__ __launch_bounds__(256) void k_gemm(const float* __restrict__ A,
                                              const float* __restrict__ Bw,
                                              float* __restrict__ C,
                                              int M, int K, int Nc,
                                              const float* __restrict__ bias) {
    __shared__ float As[16][65];
    __shared__ float Bs[16][65];
    int bm = blockIdx.x * 64;
    int bn = blockIdx.y * 64;
    int tid = threadIdx.x;
    int tx = tid & 15, ty = tid >> 4;
    float acc[4][4] = {};
    for (int k0 = 0; k0 < K; k0 += 16) {
        #pragma unroll
        for (int p = 0; p < 4; p++) {
            int r = (tid >> 4) + p * 16;
            int c = tid & 15;
            int gr = bm + r;
            As[c][r] = (gr < M) ? A[(size_t)gr * K + k0 + c] : 0.f;
        }
        #pragma unroll
        for (int p = 0; p < 4; p++) {
            int kk = (tid >> 6) + p * 4;
            int n  = tid & 63;
            int gn = bn + n;
            Bs[kk][n] = (gn < Nc) ? Bw[(size_t)(k0 + kk) * Nc + gn] : 0.f;
        }
        __syncthreads();
        #pragma unroll
        for (int kk = 0; kk < 16; kk++) {
            float a0[4], b0[4];
            #pragma unroll
            for (int i = 0; i < 4; i++) a0[i] = As[kk][ty * 4 + i];
            #pragma unroll
            for (int j = 0; j < 4; j++) b0[j] = Bs[kk][tx * 4 + j];
            #pragma unroll
            for (int i = 0; i < 4; i++)
                #pragma unroll
                for (int j = 0; j < 4; j++) acc[i][j] += a0[i] * b0[j];
        }
        __syncthreads();
    }
    #pragma unroll
    for (int i = 0; i < 4; i++) {
        int gr = bm + ty * 4 + i;
        if (gr >= M) continue;
        #pragma unroll
        for (int j = 0; j < 4; j++) {
            int gn = bn + tx * 4 + j;
            if (gn < Nc) {
                float v = acc[i][j];
                if (bias) v += bias[gn];
                C[(size_t)gr * Nc + gn] = v;
            }
        }
    }
}

// ---------------------------------------------------------------- aggregation
// out[i][f] = dis[i] * sum_e val[e]*H[col[e]][f] + di[i]*H[i][f] (+ bias[f])
// d threads per node (d in {32,64,128,256}), 256-thread blocks.

__global__ __launch_bounds__(256) void k_agg(const float* __restrict__ H,
                                             float* __restrict__ out,
                                             const int* __restrict__ rowptr,
                                             const int* __restrict__ degcnt,
                                             const int* __restrict__ colv,
                                             const float* __restrict__ valv,
                                             const float* __restrict__ dis,
                                             const float* __restrict__ di,
                                             const float* __restrict__ bias,
                                             int d) {
    int G = 256 / d;
    int g = threadIdx.x / d;
    int f = threadIdx.x & (d - 1);
    int i = blockIdx.x * G + g;
    if (i >= NN) return;
    int beg = rowptr[i];
    int cnt = degcnt[i];
    float acc = 0.f;
    for (int e = 0; e < cnt; e++) {
        int c   = colv[beg + e];
        float w = valv[beg + e];
        acc += w * H[(size_t)c * d + f];
    }
    float hs = H[(size_t)i * d + f];
    float o = dis[i] * acc + di[i] * hs;
    if (bias) o += bias[f];
    out[(size_t)i * d + f] = o;
}

// ---------------------------------------------------------------- BatchNorm

__global__ __launch_bounds__(256) void k_bnstat(const float* __restrict__ Xc,
                                                float* __restrict__ bn, int d,
                                                int rows_per_blk) {
    int rpt = 256 / d;
    int f  = threadIdx.x & (d - 1);
    int r0 = threadIdx.x / d;
    int base = blockIdx.x * rows_per_blk;
    float s = 0.f, s2 = 0.f;
    for (int r = r0; r < rows_per_blk; r += rpt) {
        int i = base + r;
        if (i < NN) {
            float v = Xc[(size_t)i * d + f];
            s += v; s2 += v * v;
        }
    }
    __shared__ float ls[256], ls2[256];
    ls[threadIdx.x] = s; ls2[threadIdx.x] = s2;
    __syncthreads();
    if (threadIdx.x < d) {
        float a = 0.f, b = 0.f;
        for (int g = 0; g < rpt; g++) { a += ls[g * d + threadIdx.x]; b += ls2[g * d + threadIdx.x]; }
        atomicAdd(&bn[threadIdx.x], a);
        atomicAdd(&bn[d + threadIdx.x], b);
    }
}

__global__ void k_bnfin(const float* __restrict__ bn, const float* __restrict__ g,
                        const float* __restrict__ be, float* __restrict__ AB, int d) {
    int f = threadIdx.x;
    if (f < d) {
        float mu  = bn[f] / (float)NN;
        float var = bn[d + f] / (float)NN - mu * mu;
        var = fmaxf(var, 0.f);
        float inv = rsqrtf(var + EPSB);
        float a = g[f] * inv;
        AB[f]     = a;
        AB[d + f] = be[f] - mu * a;
    }
}

__global__ void k_norm(float* __restrict__ X, const float* __restrict__ AB,
                       int d, int total) {
    int idx = blockIdx.x * blockDim.x + threadIdx.x;
    if (idx < total) {
        int f = idx & (d - 1);
        float v = X[idx] * AB[f] + AB[d + f];
        X[idx] = fmaxf(v, 0.f);
    }
}

// ---------------------------------------------------------------- final edge MLP

__global__ __launch_bounds__(256) void k_edge(const float* __restrict__ X,
                                              const int* __restrict__ src,
                                              const int* __restrict__ dst,
                                              const float* __restrict__ fcw,
                                              const float* __restrict__ fcb,
                                              float* __restrict__ out) {
    int lane = threadIdx.x & 31;
    int eid = (int)(((size_t)blockIdx.x * blockDim.x + threadIdx.x) >> 5);
    if (eid >= EE) return;
    int s = src[eid], d = dst[eid];
    float v = X[(size_t)s * 32 + lane] * X[(size_t)d * 32 + lane] * fcw[lane];
    #pragma unroll
    for (int off = 16; off; off >>= 1) v += __shfl_xor(v, off, 32);
    if (lane == 0) out[eid] = 1.f / (1.f + expf(-(v + fcb[0])));
}

// ---------------------------------------------------------------- launch

extern "C" void kernel_launch(void* const* d_in, const int* in_sizes, int n_in,
                              void* d_out, int out_size, void* d_ws, size_t ws_size,
                              hipStream_t stream) {
    const float* x0 = (const float*)d_in[0];
    const int* ei   = (const int*)d_in[1];
    const int* srcv = ei;
    const int* dstv = ei + EE;
    const float *W[5], *bp[5], *gp[5], *bep[5];
    int idx = 2;
    for (int l = 0; l < 5; l++) {
        W[l]   = (const float*)d_in[idx++];
        bp[l]  = (const float*)d_in[idx++];
        gp[l]  = (const float*)d_in[idx++];
        bep[l] = (const float*)d_in[idx++];
    }
    const float* fcw = (const float*)d_in[22];
    const float* fcb = (const float*)d_in[23];

    char* ws = (char*)d_ws;
    size_t off = 0;
    auto alloc = [&](size_t bytes) -> void* {
        void* p = ws + off;
        off = (off + bytes + 255) & ~(size_t)255;
        return p;
    };
    float* bufA   = (float*)alloc((size_t)NN * 256 * 4);
    float* bufB   = (float*)alloc((size_t)NN * 256 * 4);
    int*   colv   = (int*)  alloc((size_t)EE * 4);
    float* valv   = (float*)alloc((size_t)EE * 4);
    int*   rowptr = (int*)  alloc((size_t)NN * 4);
    int*   degcnt = (int*)  alloc((size_t)NN * 4);
    int*   cursor = (int*)  alloc((size_t)NN * 4);
    float* dis    = (float*)alloc((size_t)NN * 4);
    float* di     = (float*)alloc((size_t)NN * 4);
    int*   scnblk = (int*)  alloc(4096);
    float* bn     = (float*)alloc(512 * 4);
    float* bnAB   = (float*)alloc(512 * 4);

    hipMemsetAsync(degcnt, 0, (size_t)NN * 4, stream);
    hipMemsetAsync(cursor, 0, (size_t)NN * 4, stream);

    k_hist<<<(EE + 255) / 256, 256, 0, stream>>>(dstv, degcnt);
    k_deg<<<(NN + 255) / 256, 256, 0, stream>>>(degcnt, dis, di);
    int nScanBlk = (NN + 1023) / 1024;  // 98
    k_scan_block<<<nScanBlk, 1024, 0, stream>>>(degcnt, rowptr, scnblk, NN);
    k_scan_top<<<1, 64, 0, stream>>>(scnblk, nScanBlk);
    k_scan_add<<<nScanBlk, 1024, 0, stream>>>(rowptr, scnblk, NN);
    k_fill<<<(EE + 255) / 256, 256, 0, stream>>>(srcv, dstv, rowptr, cursor, colv, valv, dis);

    const int dims[6] = {128, 128, 256, 128, 64, 32};
    const int aggFirst[5] = {0, 1, 0, 0, 0};

    const float* xin = x0;
    for (int l = 0; l < 5; l++) {
        int din = dims[l], dout = dims[l + 1];
        if (aggFirst[l]) {
            int G = 256 / din;
            k_agg<<<(NN + G - 1) / G, 256, 0, stream>>>(xin, bufA, rowptr, degcnt,
                                                        colv, valv, dis, di, nullptr, din);
            dim3 grid((NN + 63) / 64, (dout + 63) / 64);
            k_gemm<<<grid, 256, 0, stream>>>(bufA, W[l], bufB, NN, din, dout, bp[l]);
        } else {
            dim3 grid((NN + 63) / 64, (dout + 63) / 64);
            k_gemm<<<grid, 256, 0, stream>>>(xin, W[l], bufA, NN, din, dout, nullptr);
            int G = 256 / dout;
            k_agg<<<(NN + G - 1) / G, 256, 0, stream>>>(bufA, bufB, rowptr, degcnt,
                                                        colv, valv, dis, di, bp[l], dout);
        }
        hipMemsetAsync(bn, 0, (size_t)2 * dout * 4, stream);
        k_bnstat<<<(NN + 511) / 512, 256, 0, stream>>>(bufB, bn, dout, 512);
        k_bnfin<<<1, 256, 0, stream>>>(bn, gp[l], bep[l], bnAB, dout);
        int total = NN * dout;
        k_norm<<<(total + 255) / 256, 256, 0, stream>>>(bufB, bnAB, dout, total);
        xin = bufB;
    }

    size_t edgeThreads = (size_t)EE * 32;
    k_edge<<<(unsigned)((edgeThreads + 255) / 256), 256, 0, stream>>>(
        bufB, srcv, dstv, fcw, fcb, (float*)d_out);
}

// Round 2
// 2403.547 us; speedup vs baseline: 1.5480x; 1.5480x over previous
//
#include <hip/hip_runtime.h>
#include <hip/hip_bf16.h>
#include <cstddef>

#define NN 100000
#define EE 3200000
#define EPSB 1e-5f

// ---------------------------------------------------------------- CSR build

__global__ void k_hist(const int* __restrict__ dst, int* __restrict__ degcnt) {
    int e = blockIdx.x * blockDim.x + threadIdx.x;
    if (e < EE) atomicAdd(&degcnt[dst[e]], 1);
}

__global__ void k_deg(const int* __restrict__ degcnt, float* __restrict__ dis,
                      float* __restrict__ di) {
    int i = blockIdx.x * blockDim.x + threadIdx.x;
    if (i < NN) {
        float d = (float)degcnt[i] + 1.0f;
        di[i]  = 1.0f / d;
        dis[i] = rsqrtf(d);
    }
}

__global__ void k_scan_block(const int* __restrict__ in, int* __restrict__ out,
                             int* __restrict__ blksum, int n) {
    __shared__ int s[1024];
    int i = blockIdx.x * 1024 + threadIdx.x;
    int v = (i < n) ? in[i] : 0;
    s[threadIdx.x] = v;
    __syncthreads();
    for (int off = 1; off < 1024; off <<= 1) {
        int t = (threadIdx.x >= off) ? s[threadIdx.x - off] : 0;
        __syncthreads();
        s[threadIdx.x] += t;
        __syncthreads();
    }
    if (i < n) out[i] = s[threadIdx.x] - v;  // exclusive
    if (threadIdx.x == 1023) blksum[blockIdx.x] = s[1023];
}

__global__ void k_scan_top(int* __restrict__ blksum, int nb) {
    if (threadIdx.x == 0) {
        int acc = 0;
        for (int b = 0; b < nb; b++) { int v = blksum[b]; blksum[b] = acc; acc += v; }
    }
}

__global__ void k_scan_add(int* __restrict__ out, const int* __restrict__ blksum, int n) {
    int i = blockIdx.x * 1024 + threadIdx.x;
    if (i < n) out[i] += blksum[blockIdx.x];
}

__global__ void k_fill(const int* __restrict__ src, const int* __restrict__ dst,
                       const int* __restrict__ rowptr, int* __restrict__ cursor,
                       int* __restrict__ col, float* __restrict__ val,
                       const float* __restrict__ dis) {
    int e = blockIdx.x * blockDim.x + threadIdx.x;
    if (e < EE) {
        int d = dst[e], s = src[e];
        int pos = rowptr[d] + atomicAdd(&cursor[d], 1);
        col[pos] = s;
        val[pos] = dis[s];
    }
}

// ---------------------------------------------------------------- GEMM (fp32)
// C[M,Nc] = A[M,K] @ B[K,Nc] (+ bias). BM=BN=64, BK=16, 256 thr, 4x4/thread.

__global__ __launch_bounds__(256) void k_gemm(const float* __restrict__ A,
                                              const float* __restrict__ Bw,
                                              float* __restrict__ C,
                                              int M, int K, int Nc,
                                              const float* __restrict__ bias) {
    __shared__ float As[16][65];
    __shared__ float Bs[16][65];
    int bm = blockIdx.x * 64;
    int bn = blockIdx.y * 64;
    int tid = threadIdx.x;
    int tx = tid & 15, ty = tid >> 4;
    float acc[4][4] = {};
    for (int k0 = 0; k0 < K; k0 += 16) {
        #pragma unroll
        for (int p = 0; p < 4; p++) {
            int r = (tid >> 4) + p * 16;
            int c = tid & 15;
            int gr = bm + r;
            As[c][r] = (gr < M) ? A[(size_t)gr * K + k0 + c] : 0.f;
        }
        #pragma unroll
        for (int p = 0; p < 4; p++) {
            int kk = (tid >> 6) + p * 4;
            int n  = tid & 63;
            int gn = bn + n;
            Bs[kk][n] = (gn < Nc) ? Bw[(size_t)(k0 + kk) * Nc + gn] : 0.f;
        }
        __syncthreads();
        #pragma unroll
        for (int kk = 0; kk < 16; kk++) {
            float a0[4], b0[4];
            #pragma unroll
            for (int i = 0; i < 4; i++) a0[i] = As[kk][ty * 4 + i];
            #pragma unroll
            for (int j = 0; j < 4; j++) b0[j] = Bs[kk][tx * 4 + j];
            #pragma unroll
            for (int i = 0; i < 4; i++)
                #pragma unroll
                for (int j = 0; j < 4; j++) acc[i][j] += a0[i] * b0[j];
        }
        __syncthreads();
    }
    #pragma unroll
    for (int i = 0; i < 4; i++) {
        int gr = bm + ty * 4 + i;
        if (gr >= M) continue;
        #pragma unroll
        for (int j = 0; j < 4; j++) {
            int gn = bn + tx * 4 + j;
            if (gn < Nc) {
                float v = acc[i][j];
                if (bias) v += bias[gn];
                C[(size_t)gr * Nc + gn] = v;
            }
        }
    }
}

// ---------------------------------------------------------------- aggregation
// out[i][:] = dis[i] * sum_e val[e]*H[col[e]][:] + di[i]*H[i][:] (+ bias)
// float4 per thread, TPN = d/4 threads per node, 8-edge batching for MLP.

template<int TPN>
__global__ __launch_bounds__(256) void k_agg_v(const float4* __restrict__ H,
                                               float4* __restrict__ out,
                                               const int* __restrict__ rowptr,
                                               const int* __restrict__ degcnt,
                                               const int* __restrict__ colv,
                                               const float* __restrict__ valv,
                                               const float* __restrict__ dis,
                                               const float* __restrict__ di,
                                               const float* __restrict__ bias) {
    constexpr int G = 256 / TPN;
    int g    = threadIdx.x / TPN;
    int lane = threadIdx.x % TPN;
    int i = blockIdx.x * G + g;
    if (i >= NN) return;
    int beg = rowptr[i];
    int cnt = degcnt[i];
    float4 acc = {0.f, 0.f, 0.f, 0.f};
    int e = 0;
    for (; e + 8 <= cnt; e += 8) {
        int   c[8];
        float w[8];
        #pragma unroll
        for (int j = 0; j < 8; j++) {
            c[j] = colv[beg + e + j];
            w[j] = valv[beg + e + j];
        }
        float4 h[8];
        #pragma unroll
        for (int j = 0; j < 8; j++) h[j] = H[(size_t)c[j] * TPN + lane];
        #pragma unroll
        for (int j = 0; j < 8; j++) {
            acc.x += w[j] * h[j].x;
            acc.y += w[j] * h[j].y;
            acc.z += w[j] * h[j].z;
            acc.w += w[j] * h[j].w;
        }
    }
    for (; e < cnt; e++) {
        int   c = colv[beg + e];
        float w = valv[beg + e];
        float4 h = H[(size_t)c * TPN + lane];
        acc.x += w * h.x; acc.y += w * h.y; acc.z += w * h.z; acc.w += w * h.w;
    }
    float4 hs = H[(size_t)i * TPN + lane];
    float ds = dis[i], dii = di[i];
    float4 o;
    o.x = ds * acc.x + dii * hs.x;
    o.y = ds * acc.y + dii * hs.y;
    o.z = ds * acc.z + dii * hs.z;
    o.w = ds * acc.w + dii * hs.w;
    if (bias) {
        float4 b4 = ((const float4*)bias)[lane];
        o.x += b4.x; o.y += b4.y; o.z += b4.z; o.w += b4.w;
    }
    out[(size_t)i * TPN + lane] = o;
}

// ---------------------------------------------------------------- BatchNorm

__global__ __launch_bounds__(256) void k_bnstat(const float* __restrict__ Xc,
                                                float* __restrict__ bn, int d,
                                                int rows_per_blk) {
    int rpt = 256 / d;
    int f  = threadIdx.x & (d - 1);
    int r0 = threadIdx.x / d;
    int base = blockIdx.x * rows_per_blk;
    float s = 0.f, s2 = 0.f;
    for (int r = r0; r < rows_per_blk; r += rpt) {
        int i = base + r;
        if (i < NN) {
            float v = Xc[(size_t)i * d + f];
            s += v; s2 += v * v;
        }
    }
    __shared__ float ls[256], ls2[256];
    ls[threadIdx.x] = s; ls2[threadIdx.x] = s2;
    __syncthreads();
    if (threadIdx.x < d) {
        float a = 0.f, b = 0.f;
        for (int g = 0; g < rpt; g++) { a += ls[g * d + threadIdx.x]; b += ls2[g * d + threadIdx.x]; }
        atomicAdd(&bn[threadIdx.x], a);
        atomicAdd(&bn[d + threadIdx.x], b);
    }
}

__global__ void k_bnfin(const float* __restrict__ bn, const float* __restrict__ g,
                        const float* __restrict__ be, float* __restrict__ AB, int d) {
    int f = threadIdx.x;
    if (f < d) {
        float mu  = bn[f] / (float)NN;
        float var = bn[d + f] / (float)NN - mu * mu;
        var = fmaxf(var, 0.f);
        float inv = rsqrtf(var + EPSB);
        float a = g[f] * inv;
        AB[f]     = a;
        AB[d + f] = be[f] - mu * a;
    }
}

__global__ void k_norm(float* __restrict__ X, const float* __restrict__ AB,
                       int d, int total) {
    int idx = blockIdx.x * blockDim.x + threadIdx.x;
    if (idx < total) {
        int f = idx & (d - 1);
        float v = X[idx] * AB[f] + AB[d + f];
        X[idx] = fmaxf(v, 0.f);
    }
}

// ---------------------------------------------------------------- final edge MLP
// d=32 -> 8 float4 per row; 8 lanes per edge.

__global__ __launch_bounds__(256) void k_edge(const float4* __restrict__ X,
                                              const int* __restrict__ src,
                                              const int* __restrict__ dst,
                                              const float* __restrict__ fcw,
                                              const float* __restrict__ fcb,
                                              float* __restrict__ out) {
    int lane = threadIdx.x & 7;
    size_t t = (size_t)blockIdx.x * 256 + threadIdx.x;
    int eid = (int)(t >> 3);
    if (eid >= EE) return;
    int s = src[eid], d = dst[eid];
    float4 a = X[(size_t)s * 8 + lane];
    float4 b = X[(size_t)d * 8 + lane];
    float4 w = ((const float4*)fcw)[lane];
    float v = a.x * b.x * w.x + a.y * b.y * w.y + a.z * b.z * w.z + a.w * b.w * w.w;
    v += __shfl_xor(v, 1, 8);
    v += __shfl_xor(v, 2, 8);
    v += __shfl_xor(v, 4, 8);
    if (lane == 0) out[eid] = 1.f / (1.f + expf(-(v + fcb[0])));
}

// ---------------------------------------------------------------- launch

static inline void launch_agg(int d, const float* H, float* out,
                              const int* rowptr, const int* degcnt,
                              const int* colv, const float* valv,
                              const float* dis, const float* di,
                              const float* bias, hipStream_t stream) {
    if (d == 128) {
        constexpr int TPN = 32, G = 256 / TPN;
        k_agg_v<TPN><<<(NN + G - 1) / G, 256, 0, stream>>>(
            (const float4*)H, (float4*)out, rowptr, degcnt, colv, valv, dis, di, bias);
    } else if (d == 64) {
        constexpr int TPN = 16, G = 256 / TPN;
        k_agg_v<TPN><<<(NN + G - 1) / G, 256, 0, stream>>>(
            (const float4*)H, (float4*)out, rowptr, degcnt, colv, valv, dis, di, bias);
    } else if (d == 32) {
        constexpr int TPN = 8, G = 256 / TPN;
        k_agg_v<TPN><<<(NN + G - 1) / G, 256, 0, stream>>>(
            (const float4*)H, (float4*)out, rowptr, degcnt, colv, valv, dis, di, bias);
    } else { // d == 256
        constexpr int TPN = 64, G = 256 / TPN;
        k_agg_v<TPN><<<(NN + G - 1) / G, 256, 0, stream>>>(
            (const float4*)H, (float4*)out, rowptr, degcnt, colv, valv, dis, di, bias);
    }
}

extern "C" void kernel_launch(void* const* d_in, const int* in_sizes, int n_in,
                              void* d_out, int out_size, void* d_ws, size_t ws_size,
                              hipStream_t stream) {
    const float* x0 = (const float*)d_in[0];
    const int* ei   = (const int*)d_in[1];
    const int* srcv = ei;
    const int* dstv = ei + EE;
    const float *W[5], *bp[5], *gp[5], *bep[5];
    int idx = 2;
    for (int l = 0; l < 5; l++) {
        W[l]   = (const float*)d_in[idx++];
        bp[l]  = (const float*)d_in[idx++];
        gp[l]  = (const float*)d_in[idx++];
        bep[l] = (const float*)d_in[idx++];
    }
    const float* fcw = (const float*)d_in[22];
    const float* fcb = (const float*)d_in[23];

    char* ws = (char*)d_ws;
    size_t off = 0;
    auto alloc = [&](size_t bytes) -> void* {
        void* p = ws + off;
        off = (off + bytes + 255) & ~(size_t)255;
        return p;
    };
    float* bufA   = (float*)alloc((size_t)NN * 256 * 4);
    float* bufB   = (float*)alloc((size_t)NN * 256 * 4);
    int*   colv   = (int*)  alloc((size_t)EE * 4);
    float* valv   = (float*)alloc((size_t)EE * 4);
    int*   rowptr = (int*)  alloc((size_t)NN * 4);
    int*   degcnt = (int*)  alloc((size_t)NN * 4);
    int*   cursor = (int*)  alloc((size_t)NN * 4);
    float* dis    = (float*)alloc((size_t)NN * 4);
    float* di     = (float*)alloc((size_t)NN * 4);
    int*   scnblk = (int*)  alloc(4096);
    float* bn     = (float*)alloc(512 * 4);
    float* bnAB   = (float*)alloc(512 * 4);

    hipMemsetAsync(degcnt, 0, (size_t)NN * 4, stream);
    hipMemsetAsync(cursor, 0, (size_t)NN * 4, stream);

    k_hist<<<(EE + 255) / 256, 256, 0, stream>>>(dstv, degcnt);
    k_deg<<<(NN + 255) / 256, 256, 0, stream>>>(degcnt, dis, di);
    int nScanBlk = (NN + 1023) / 1024;  // 98
    k_scan_block<<<nScanBlk, 1024, 0, stream>>>(degcnt, rowptr, scnblk, NN);
    k_scan_top<<<1, 64, 0, stream>>>(scnblk, nScanBlk);
    k_scan_add<<<nScanBlk, 1024, 0, stream>>>(rowptr, scnblk, NN);
    k_fill<<<(EE + 255) / 256, 256, 0, stream>>>(srcv, dstv, rowptr, cursor, colv, valv, dis);

    const int dims[6] = {128, 128, 256, 128, 64, 32};
    const int aggFirst[5] = {0, 1, 0, 0, 0};

    const float* xin = x0;
    for (int l = 0; l < 5; l++) {
        int din = dims[l], dout = dims[l + 1];
        if (aggFirst[l]) {
            launch_agg(din, xin, bufA, rowptr, degcnt, colv, valv, dis, di, nullptr, stream);
            dim3 grid((NN + 63) / 64, (dout + 63) / 64);
            k_gemm<<<grid, 256, 0, stream>>>(bufA, W[l], bufB, NN, din, dout, bp[l]);
        } else {
            dim3 grid((NN + 63) / 64, (dout + 63) / 64);
            k_gemm<<<grid, 256, 0, stream>>>(xin, W[l], bufA, NN, din, dout, nullptr);
            launch_agg(dout, bufA, bufB, rowptr, degcnt, colv, valv, dis, di, bp[l], stream);
        }
        hipMemsetAsync(bn, 0, (size_t)2 * dout * 4, stream);
        k_bnstat<<<(NN + 511) / 512, 256, 0, stream>>>(bufB, bn, dout, 512);
        k_bnfin<<<1, 256, 0, stream>>>(bn, gp[l], bep[l], bnAB, dout);
        int total = NN * dout;
        k_norm<<<(total + 255) / 256, 256, 0, stream>>>(bufB, bnAB, dout, total);
        xin = bufB;
    }

    size_t edgeThreads = (size_t)EE * 8;
    k_edge<<<(unsigned)((edgeThreads + 255) / 256), 256, 0, stream>>>(
        (const float4*)bufB, srcv, dstv, fcw, fcb, (float*)d_out);
}

// Round 3
// 2032.018 us; speedup vs baseline: 1.8310x; 1.1828x over previous
//
#include <hip/hip_runtime.h>
#include <hip/hip_fp16.h>
#include <cstddef>

#define NN 100000
#define EE 3200000
#define EPSB 1e-5f

// ---------------------------------------------------------------- CSR build

__global__ void k_hist(const int* __restrict__ dst, int* __restrict__ degcnt) {
    int e = blockIdx.x * blockDim.x + threadIdx.x;
    if (e < EE) atomicAdd(&degcnt[dst[e]], 1);
}

__global__ void k_deg(const int* __restrict__ degcnt, float* __restrict__ dis) {
    int i = blockIdx.x * blockDim.x + threadIdx.x;
    if (i < NN) {
        float d = (float)degcnt[i] + 1.0f;
        dis[i] = rsqrtf(d);
    }
}

__global__ void k_scan_block(const int* __restrict__ in, int* __restrict__ out,
                             int* __restrict__ blksum, int n) {
    __shared__ int s[1024];
    int i = blockIdx.x * 1024 + threadIdx.x;
    int v = (i < n) ? in[i] : 0;
    s[threadIdx.x] = v;
    __syncthreads();
    for (int off = 1; off < 1024; off <<= 1) {
        int t = (threadIdx.x >= off) ? s[threadIdx.x - off] : 0;
        __syncthreads();
        s[threadIdx.x] += t;
        __syncthreads();
    }
    if (i < n) out[i] = s[threadIdx.x] - v;  // exclusive
    if (threadIdx.x == 1023) blksum[blockIdx.x] = s[1023];
}

__global__ void k_scan_top(int* __restrict__ blksum, int nb) {
    if (threadIdx.x == 0) {
        int acc = 0;
        for (int b = 0; b < nb; b++) { int v = blksum[b]; blksum[b] = acc; acc += v; }
    }
}

__global__ void k_scan_add(int* __restrict__ out, const int* __restrict__ blksum, int n) {
    int i = blockIdx.x * 1024 + threadIdx.x;
    if (i < n) out[i] += blksum[blockIdx.x];
}

// cursor pre-initialized to rowptr (d2d copy); one atomic + one 4B store.
__global__ void k_fill(const int* __restrict__ src, const int* __restrict__ dst,
                       int* __restrict__ cursor, int* __restrict__ col) {
    int e = blockIdx.x * blockDim.x + threadIdx.x;
    if (e < EE) {
        int pos = atomicAdd(&cursor[dst[e]], 1);
        col[pos] = src[e];
    }
}

// ---------------------------------------------------------------- GEMMs
// Common core: C[M,Nc] = A[M,K]@B[K,Nc]. BM=BN=64, BK=16, 256 thr, 4x4/thread.

// fp32 output + bias (layer 1 only)
__global__ __launch_bounds__(256) void k_gemm_f(const float* __restrict__ A,
                                                const float* __restrict__ Bw,
                                                float* __restrict__ C,
                                                int M, int K, int Nc,
                                                const float* __restrict__ bias) {
    __shared__ float As[16][65];
    __shared__ float Bs[16][65];
    int bm = blockIdx.x * 64;
    int bn = blockIdx.y * 64;
    int tid = threadIdx.x;
    int tx = tid & 15, ty = tid >> 4;
    float acc[4][4] = {};
    for (int k0 = 0; k0 < K; k0 += 16) {
        #pragma unroll
        for (int p = 0; p < 4; p++) {
            int r = (tid >> 4) + p * 16;
            int c = tid & 15;
            int gr = bm + r;
            As[c][r] = (gr < M) ? A[(size_t)gr * K + k0 + c] : 0.f;
        }
        #pragma unroll
        for (int p = 0; p < 4; p++) {
            int kk = (tid >> 6) + p * 4;
            int n  = tid & 63;
            int gn = bn + n;
            Bs[kk][n] = (gn < Nc) ? Bw[(size_t)(k0 + kk) * Nc + gn] : 0.f;
        }
        __syncthreads();
        #pragma unroll
        for (int kk = 0; kk < 16; kk++) {
            float a0[4], b0[4];
            #pragma unroll
            for (int i = 0; i < 4; i++) a0[i] = As[kk][ty * 4 + i];
            #pragma unroll
            for (int j = 0; j < 4; j++) b0[j] = Bs[kk][tx * 4 + j];
            #pragma unroll
            for (int i = 0; i < 4; i++)
                #pragma unroll
                for (int j = 0; j < 4; j++) acc[i][j] += a0[i] * b0[j];
        }
        __syncthreads();
    }
    #pragma unroll
    for (int i = 0; i < 4; i++) {
        int gr = bm + ty * 4 + i;
        if (gr >= M) continue;
        #pragma unroll
        for (int j = 0; j < 4; j++) {
            int gn = bn + tx * 4 + j;
            if (gn < Nc) C[(size_t)gr * Nc + gn] = acc[i][j] + bias[gn];
        }
    }
}

// fp16 output, row-scaled by dis[gr] (staged aggregation operand)
__global__ __launch_bounds__(256) void k_gemm_h(const float* __restrict__ A,
                                                const float* __restrict__ Bw,
                                                __half* __restrict__ C,
                                                int M, int K, int Nc,
                                                const float* __restrict__ dis) {
    __shared__ float As[16][65];
    __shared__ float Bs[16][65];
    int bm = blockIdx.x * 64;
    int bn = blockIdx.y * 64;
    int tid = threadIdx.x;
    int tx = tid & 15, ty = tid >> 4;
    float acc[4][4] = {};
    for (int k0 = 0; k0 < K; k0 += 16) {
        #pragma unroll
        for (int p = 0; p < 4; p++) {
            int r = (tid >> 4) + p * 16;
            int c = tid & 15;
            int gr = bm + r;
            As[c][r] = (gr < M) ? A[(size_t)gr * K + k0 + c] : 0.f;
        }
        #pragma unroll
        for (int p = 0; p < 4; p++) {
            int kk = (tid >> 6) + p * 4;
            int n  = tid & 63;
            int gn = bn + n;
            Bs[kk][n] = (gn < Nc) ? Bw[(size_t)(k0 + kk) * Nc + gn] : 0.f;
        }
        __syncthreads();
        #pragma unroll
        for (int kk = 0; kk < 16; kk++) {
            float a0[4], b0[4];
            #pragma unroll
            for (int i = 0; i < 4; i++) a0[i] = As[kk][ty * 4 + i];
            #pragma unroll
            for (int j = 0; j < 4; j++) b0[j] = Bs[kk][tx * 4 + j];
            #pragma unroll
            for (int i = 0; i < 4; i++)
                #pragma unroll
                for (int j = 0; j < 4; j++) acc[i][j] += a0[i] * b0[j];
        }
        __syncthreads();
    }
    #pragma unroll
    for (int i = 0; i < 4; i++) {
        int gr = bm + ty * 4 + i;
        if (gr >= M) continue;
        float ds = dis[gr];
        int gn0 = bn + tx * 4;
        if (gn0 < Nc) {  // Nc % 4 == 0 -> whole half4 in or out
            __half2 h01 = __floats2half2_rn(ds * acc[i][0], ds * acc[i][1]);
            __half2 h23 = __floats2half2_rn(ds * acc[i][2], ds * acc[i][3]);
            union { __half2 h; unsigned u; } a, b;
            a.h = h01; b.h = h23;
            *(uint2*)&C[(size_t)gr * Nc + gn0] = make_uint2(a.u, b.u);
        }
    }
}

// layer-1 staging: Hs = fp16(dis[i] * x[i][:])  (d = 128)
__global__ void k_scale_h(const float4* __restrict__ X, const float* __restrict__ dis,
                          uint2* __restrict__ out) {
    int t = blockIdx.x * blockDim.x + threadIdx.x;
    if (t >= NN * 32) return;
    int row = t >> 5;  // 32 float4 per row
    float ds = dis[row];
    float4 v = X[t];
    union { __half2 h; unsigned u; } a, b;
    a.h = __floats2half2_rn(ds * v.x, ds * v.y);
    b.h = __floats2half2_rn(ds * v.z, ds * v.w);
    out[t] = make_uint2(a.u, b.u);
}

// ---------------------------------------------------------------- aggregation
// Hs rows are fp16, pre-scaled by dis[src]. TPN = d/8 threads/node, 16B/thread.
// out[i][:] = dis[i] * (sum_e Hs[col[e]][:] + Hs[i][:]) + bias

__device__ __forceinline__ void acc_row(float* acc, const uint4& r) {
    const __half2* hp = (const __half2*)&r;
    #pragma unroll
    for (int k = 0; k < 4; k++) {
        float2 f2 = __half22float2(hp[k]);
        acc[2 * k]     += f2.x;
        acc[2 * k + 1] += f2.y;
    }
}

template<int TPN>
__global__ __launch_bounds__(256) void k_agg_h(const uint4* __restrict__ Hs,
                                               float4* __restrict__ out,
                                               const int* __restrict__ rowptr,
                                               const int* __restrict__ degcnt,
                                               const int* __restrict__ colv,
                                               const float* __restrict__ dis,
                                               const float* __restrict__ bias) {
    constexpr int G = 256 / TPN;
    int g    = threadIdx.x / TPN;
    int lane = threadIdx.x % TPN;
    int i = blockIdx.x * G + g;
    if (i >= NN) return;
    int beg = rowptr[i];
    int cnt = degcnt[i];
    const uint4* base = Hs + lane;
    float acc[8] = {};
    int e = 0;
    for (; e + 8 <= cnt; e += 8) {
        int c[8];
        #pragma unroll
        for (int j = 0; j < 8; j++) c[j] = colv[beg + e + j];
        uint4 r[8];
        #pragma unroll
        for (int j = 0; j < 8; j++) r[j] = base[(size_t)c[j] * TPN];
        #pragma unroll
        for (int j = 0; j < 8; j++) acc_row(acc, r[j]);
    }
    for (; e < cnt; e++) {
        int c = colv[beg + e];
        uint4 r = base[(size_t)c * TPN];
        acc_row(acc, r);
    }
    uint4 rs = base[(size_t)i * TPN];  // self-loop
    acc_row(acc, rs);
    float ds = dis[i];
    float o[8];
    #pragma unroll
    for (int k = 0; k < 8; k++) o[k] = ds * acc[k];
    if (bias) {
        float4 b0 = ((const float4*)bias)[lane * 2];
        float4 b1 = ((const float4*)bias)[lane * 2 + 1];
        o[0] += b0.x; o[1] += b0.y; o[2] += b0.z; o[3] += b0.w;
        o[4] += b1.x; o[5] += b1.y; o[6] += b1.z; o[7] += b1.w;
    }
    size_t ob = (size_t)i * (2 * TPN) + lane * 2;
    out[ob]     = make_float4(o[0], o[1], o[2], o[3]);
    out[ob + 1] = make_float4(o[4], o[5], o[6], o[7]);
}

// ---------------------------------------------------------------- BatchNorm

__global__ __launch_bounds__(256) void k_bnstat(const float* __restrict__ Xc,
                                                float* __restrict__ bn, int d,
                                                int rows_per_blk) {
    int rpt = 256 / d;
    int f  = threadIdx.x & (d - 1);
    int r0 = threadIdx.x / d;
    int base = blockIdx.x * rows_per_blk;
    float s = 0.f, s2 = 0.f;
    for (int r = r0; r < rows_per_blk; r += rpt) {
        int i = base + r;
        if (i < NN) {
            float v = Xc[(size_t)i * d + f];
            s += v; s2 += v * v;
        }
    }
    __shared__ float ls[256], ls2[256];
    ls[threadIdx.x] = s; ls2[threadIdx.x] = s2;
    __syncthreads();
    if (threadIdx.x < d) {
        float a = 0.f, b = 0.f;
        for (int g = 0; g < rpt; g++) { a += ls[g * d + threadIdx.x]; b += ls2[g * d + threadIdx.x]; }
        atomicAdd(&bn[threadIdx.x], a);
        atomicAdd(&bn[d + threadIdx.x], b);
    }
}

__global__ void k_bnfin(const float* __restrict__ bn, const float* __restrict__ g,
                        const float* __restrict__ be, float* __restrict__ AB, int d) {
    int f = threadIdx.x;
    if (f < d) {
        float mu  = bn[f] / (float)NN;
        float var = bn[d + f] / (float)NN - mu * mu;
        var = fmaxf(var, 0.f);
        float inv = rsqrtf(var + EPSB);
        float a = g[f] * inv;
        AB[f]     = a;
        AB[d + f] = be[f] - mu * a;
    }
}

__global__ void k_norm(float* __restrict__ X, const float* __restrict__ AB,
                       int d, int total) {
    int idx = blockIdx.x * blockDim.x + threadIdx.x;
    if (idx < total) {
        int f = idx & (d - 1);
        float v = X[idx] * AB[f] + AB[d + f];
        X[idx] = fmaxf(v, 0.f);
    }
}

// ---------------------------------------------------------------- final edge MLP

__global__ __launch_bounds__(256) void k_edge(const float4* __restrict__ X,
                                              const int* __restrict__ src,
                                              const int* __restrict__ dst,
                                              const float* __restrict__ fcw,
                                              const float* __restrict__ fcb,
                                              float* __restrict__ out) {
    int lane = threadIdx.x & 7;
    size_t t = (size_t)blockIdx.x * 256 + threadIdx.x;
    int eid = (int)(t >> 3);
    if (eid >= EE) return;
    int s = src[eid], d = dst[eid];
    float4 a = X[(size_t)s * 8 + lane];
    float4 b = X[(size_t)d * 8 + lane];
    float4 w = ((const float4*)fcw)[lane];
    float v = a.x * b.x * w.x + a.y * b.y * w.y + a.z * b.z * w.z + a.w * b.w * w.w;
    v += __shfl_xor(v, 1, 8);
    v += __shfl_xor(v, 2, 8);
    v += __shfl_xor(v, 4, 8);
    if (lane == 0) out[eid] = 1.f / (1.f + expf(-(v + fcb[0])));
}

// ---------------------------------------------------------------- launch

static inline void launch_agg(int d, const __half* Hs, float* out,
                              const int* rowptr, const int* degcnt,
                              const int* colv, const float* dis,
                              const float* bias, hipStream_t stream) {
    if (d == 128) {
        constexpr int TPN = 16, G = 256 / TPN;
        k_agg_h<TPN><<<(NN + G - 1) / G, 256, 0, stream>>>(
            (const uint4*)Hs, (float4*)out, rowptr, degcnt, colv, dis, bias);
    } else if (d == 64) {
        constexpr int TPN = 8, G = 256 / TPN;
        k_agg_h<TPN><<<(NN + G - 1) / G, 256, 0, stream>>>(
            (const uint4*)Hs, (float4*)out, rowptr, degcnt, colv, dis, bias);
    } else { // d == 32
        constexpr int TPN = 4, G = 256 / TPN;
        k_agg_h<TPN><<<(NN + G - 1) / G, 256, 0, stream>>>(
            (const uint4*)Hs, (float4*)out, rowptr, degcnt, colv, dis, bias);
    }
}

static inline void run_bn(float* X, int d, const float* g, const float* be,
                          float* bn, float* bnAB, hipStream_t stream) {
    hipMemsetAsync(bn, 0, (size_t)2 * d * 4, stream);
    k_bnstat<<<(NN + 511) / 512, 256, 0, stream>>>(X, bn, d, 512);
    k_bnfin<<<1, 256, 0, stream>>>(bn, g, be, bnAB, d);
    int total = NN * d;
    k_norm<<<(total + 255) / 256, 256, 0, stream>>>(X, bnAB, d, total);
}

extern "C" void kernel_launch(void* const* d_in, const int* in_sizes, int n_in,
                              void* d_out, int out_size, void* d_ws, size_t ws_size,
                              hipStream_t stream) {
    const float* x0 = (const float*)d_in[0];
    const int* ei   = (const int*)d_in[1];
    const int* srcv = ei;
    const int* dstv = ei + EE;
    const float *W[5], *bp[5], *gp[5], *bep[5];
    int idx = 2;
    for (int l = 0; l < 5; l++) {
        W[l]   = (const float*)d_in[idx++];
        bp[l]  = (const float*)d_in[idx++];
        gp[l]  = (const float*)d_in[idx++];
        bep[l] = (const float*)d_in[idx++];
    }
    const float* fcw = (const float*)d_in[22];
    const float* fcb = (const float*)d_in[23];

    char* ws = (char*)d_ws;
    size_t off = 0;
    auto alloc = [&](size_t bytes) -> void* {
        void* p = ws + off;
        off = (off + bytes + 255) & ~(size_t)255;
        return p;
    };
    float*  bufA   = (float*) alloc((size_t)NN * 256 * 4);  // holds up to d=256
    float*  bufB   = (float*) alloc((size_t)NN * 128 * 4);  // holds up to d=128
    __half* Hh     = (__half*)alloc((size_t)NN * 128 * 2);  // staged fp16, up to d=128
    int*    colv   = (int*)   alloc((size_t)EE * 4);
    int*    rowptr = (int*)   alloc((size_t)NN * 4);
    int*    degcnt = (int*)   alloc((size_t)NN * 4);
    int*    cursor = (int*)   alloc((size_t)NN * 4);
    float*  dis    = (float*) alloc((size_t)NN * 4);
    int*    scnblk = (int*)   alloc(4096);
    float*  bn     = (float*) alloc(512 * 4);
    float*  bnAB   = (float*) alloc(512 * 4);

    hipMemsetAsync(degcnt, 0, (size_t)NN * 4, stream);

    k_hist<<<(EE + 255) / 256, 256, 0, stream>>>(dstv, degcnt);
    k_deg<<<(NN + 255) / 256, 256, 0, stream>>>(degcnt, dis);
    int nScanBlk = (NN + 1023) / 1024;  // 98
    k_scan_block<<<nScanBlk, 1024, 0, stream>>>(degcnt, rowptr, scnblk, NN);
    k_scan_top<<<1, 64, 0, stream>>>(scnblk, nScanBlk);
    k_scan_add<<<nScanBlk, 1024, 0, stream>>>(rowptr, scnblk, NN);
    hipMemcpyAsync(cursor, rowptr, (size_t)NN * 4, hipMemcpyDeviceToDevice, stream);
    k_fill<<<(EE + 255) / 256, 256, 0, stream>>>(srcv, dstv, cursor, colv);

    // ---- layer 0: gemm_h(x0,W0)->Hh ; agg->bufA (+b0) ; BN(bufA,128)
    {
        dim3 grid((NN + 63) / 64, 128 / 64);
        k_gemm_h<<<grid, 256, 0, stream>>>(x0, W[0], Hh, NN, 128, 128, dis);
        launch_agg(128, Hh, bufA, rowptr, degcnt, colv, dis, bp[0], stream);
        run_bn(bufA, 128, gp[0], bep[0], bn, bnAB, stream);
    }
    // ---- layer 1 (agg first): scale_h(bufA)->Hh ; agg->bufB ; gemm_f(bufB,W1)+b1->bufA ; BN(bufA,256)
    {
        k_scale_h<<<(NN * 32 + 255) / 256, 256, 0, stream>>>((const float4*)bufA, dis, (uint2*)Hh);
        launch_agg(128, Hh, bufB, rowptr, degcnt, colv, dis, nullptr, stream);
        dim3 grid((NN + 63) / 64, 256 / 64);
        k_gemm_f<<<grid, 256, 0, stream>>>(bufB, W[1], bufA, NN, 128, 256, bp[1]);
        run_bn(bufA, 256, gp[1], bep[1], bn, bnAB, stream);
    }
    // ---- layer 2: gemm_h(bufA,W2)->Hh ; agg->bufB (+b2) ; BN(bufB,128)
    {
        dim3 grid((NN + 63) / 64, 128 / 64);
        k_gemm_h<<<grid, 256, 0, stream>>>(bufA, W[2], Hh, NN, 256, 128, dis);
        launch_agg(128, Hh, bufB, rowptr, degcnt, colv, dis, bp[2], stream);
        run_bn(bufB, 128, gp[2], bep[2], bn, bnAB, stream);
    }
    // ---- layer 3: gemm_h(bufB,W3)->Hh ; agg->bufA (+b3) ; BN(bufA,64)
    {
        dim3 grid((NN + 63) / 64, 64 / 64);
        k_gemm_h<<<grid, 256, 0, stream>>>(bufB, W[3], Hh, NN, 128, 64, dis);
        launch_agg(64, Hh, bufA, rowptr, degcnt, colv, dis, bp[3], stream);
        run_bn(bufA, 64, gp[3], bep[3], bn, bnAB, stream);
    }
    // ---- layer 4: gemm_h(bufA,W4)->Hh ; agg->bufB (+b4) ; BN(bufB,32)
    {
        dim3 grid((NN + 63) / 64, 1);
        k_gemm_h<<<grid, 256, 0, stream>>>(bufA, W[4], Hh, NN, 64, 32, dis);
        launch_agg(32, Hh, bufB, rowptr, degcnt, colv, dis, bp[4], stream);
        run_bn(bufB, 32, gp[4], bep[4], bn, bnAB, stream);
    }

    size_t edgeThreads = (size_t)EE * 8;
    k_edge<<<(unsigned)((edgeThreads + 255) / 256), 256, 0, stream>>>(
        (const float4*)bufB, srcv, dstv, fcw, fcb, (float*)d_out);
}

// Round 4
// 1714.847 us; speedup vs baseline: 2.1697x; 1.1850x over previous
//
#include <hip/hip_runtime.h>
#include <hip/hip_fp16.h>
#include <cstddef>

#define NN 100000
#define EE 3200000
#define EPSB 1e-5f
#define NB 391      // buckets = ceil(NN/256)
#define BCAP 10240  // per-bucket edge capacity (expected 8192, Poisson max ~8.7K)

// ---------------------------------------------------------------- CSR build
// Two-level binned counting sort: no per-edge global atomics.

// tile = 4096 edges/block, 256 threads, 16 edges/thread
__global__ __launch_bounds__(256) void k_bscat(const int* __restrict__ src,
                                               const int* __restrict__ dst,
                                               int* __restrict__ bcur,
                                               uint2* __restrict__ barr) {
    __shared__ int hist[NB];
    __shared__ int base[NB];
    int tid = threadIdx.x;
    for (int b = tid; b < NB; b += 256) hist[b] = 0;
    __syncthreads();
    int e0 = blockIdx.x * 4096;
    int d[16], s[16];
    #pragma unroll
    for (int j = 0; j < 16; j++) {
        int e = e0 + j * 256 + tid;
        if (e < EE) {
            d[j] = dst[e];
            s[j] = src[e];
            atomicAdd(&hist[d[j] >> 8], 1);
        } else d[j] = -1;
    }
    __syncthreads();
    for (int b = tid; b < NB; b += 256) {
        int c = hist[b];
        base[b] = (c > 0) ? atomicAdd(&bcur[b], c) : 0;
        hist[b] = 0;
    }
    __syncthreads();
    #pragma unroll
    for (int j = 0; j < 16; j++) {
        if (d[j] >= 0) {
            int b = d[j] >> 8;
            int r = atomicAdd(&hist[b], 1);
            barr[(size_t)b * BCAP + base[b] + r] = make_uint2((unsigned)s[j], (unsigned)d[j]);
        }
    }
}

// per-bucket degree histogram -> coalesced degcnt write
__global__ __launch_bounds__(1024) void k_bdeg(const int* __restrict__ bcur,
                                               const uint2* __restrict__ barr,
                                               int* __restrict__ degcnt) {
    __shared__ int h[256];
    int b = blockIdx.x;
    if (threadIdx.x < 256) h[threadIdx.x] = 0;
    __syncthreads();
    int cnt = bcur[b];
    const uint2* p = barr + (size_t)b * BCAP;
    for (int t = threadIdx.x; t < cnt; t += 1024)
        atomicAdd(&h[p[t].y & 255], 1);
    __syncthreads();
    if (threadIdx.x < 256) {
        int node = (b << 8) + threadIdx.x;
        if (node < NN) degcnt[node] = h[threadIdx.x];
    }
}

// per-bucket placement via LDS cursors (rowptr slice), contiguous CSR region
__global__ __launch_bounds__(1024) void k_place(const int* __restrict__ bcur,
                                                const uint2* __restrict__ barr,
                                                const int* __restrict__ rowptr,
                                                int* __restrict__ col) {
    __shared__ int cur[256];
    int b = blockIdx.x;
    if (threadIdx.x < 256) {
        int node = (b << 8) + threadIdx.x;
        cur[threadIdx.x] = (node < NN) ? rowptr[node] : 0;
    }
    __syncthreads();
    int cnt = bcur[b];
    const uint2* p = barr + (size_t)b * BCAP;
    for (int t = threadIdx.x; t < cnt; t += 1024) {
        uint2 e = p[t];
        int pos = atomicAdd(&cur[e.y & 255], 1);
        col[pos] = (int)e.x;
    }
}

__global__ void k_deg(const int* __restrict__ degcnt, float* __restrict__ dis) {
    int i = blockIdx.x * blockDim.x + threadIdx.x;
    if (i < NN) {
        float d = (float)degcnt[i] + 1.0f;
        dis[i] = rsqrtf(d);
    }
}

__global__ void k_scan_block(const int* __restrict__ in, int* __restrict__ out,
                             int* __restrict__ blksum, int n) {
    __shared__ int s[1024];
    int i = blockIdx.x * 1024 + threadIdx.x;
    int v = (i < n) ? in[i] : 0;
    s[threadIdx.x] = v;
    __syncthreads();
    for (int off = 1; off < 1024; off <<= 1) {
        int t = (threadIdx.x >= off) ? s[threadIdx.x - off] : 0;
        __syncthreads();
        s[threadIdx.x] += t;
        __syncthreads();
    }
    if (i < n) out[i] = s[threadIdx.x] - v;  // exclusive
    if (threadIdx.x == 1023) blksum[blockIdx.x] = s[1023];
}

__global__ void k_scan_top(int* __restrict__ blksum, int nb) {
    if (threadIdx.x == 0) {
        int acc = 0;
        for (int b = 0; b < nb; b++) { int v = blksum[b]; blksum[b] = acc; acc += v; }
    }
}

__global__ void k_scan_add(int* __restrict__ out, const int* __restrict__ blksum, int n) {
    int i = blockIdx.x * 1024 + threadIdx.x;
    if (i < n) out[i] += blksum[blockIdx.x];
}

// ---------------------------------------------------------------- GEMMs
// Common core: C[M,Nc] = A[M,K]@B[K,Nc]. BM=BN=64, BK=16, 256 thr, 4x4/thread.

// fp32 output + bias (layer 1 only)
__global__ __launch_bounds__(256) void k_gemm_f(const float* __restrict__ A,
                                                const float* __restrict__ Bw,
                                                float* __restrict__ C,
                                                int M, int K, int Nc,
                                                const float* __restrict__ bias) {
    __shared__ float As[16][65];
    __shared__ float Bs[16][65];
    int bm = blockIdx.x * 64;
    int bn = blockIdx.y * 64;
    int tid = threadIdx.x;
    int tx = tid & 15, ty = tid >> 4;
    float acc[4][4] = {};
    for (int k0 = 0; k0 < K; k0 += 16) {
        #pragma unroll
        for (int p = 0; p < 4; p++) {
            int r = (tid >> 4) + p * 16;
            int c = tid & 15;
            int gr = bm + r;
            As[c][r] = (gr < M) ? A[(size_t)gr * K + k0 + c] : 0.f;
        }
        #pragma unroll
        for (int p = 0; p < 4; p++) {
            int kk = (tid >> 6) + p * 4;
            int n  = tid & 63;
            int gn = bn + n;
            Bs[kk][n] = (gn < Nc) ? Bw[(size_t)(k0 + kk) * Nc + gn] : 0.f;
        }
        __syncthreads();
        #pragma unroll
        for (int kk = 0; kk < 16; kk++) {
            float a0[4], b0[4];
            #pragma unroll
            for (int i = 0; i < 4; i++) a0[i] = As[kk][ty * 4 + i];
            #pragma unroll
            for (int j = 0; j < 4; j++) b0[j] = Bs[kk][tx * 4 + j];
            #pragma unroll
            for (int i = 0; i < 4; i++)
                #pragma unroll
                for (int j = 0; j < 4; j++) acc[i][j] += a0[i] * b0[j];
        }
        __syncthreads();
    }
    #pragma unroll
    for (int i = 0; i < 4; i++) {
        int gr = bm + ty * 4 + i;
        if (gr >= M) continue;
        #pragma unroll
        for (int j = 0; j < 4; j++) {
            int gn = bn + tx * 4 + j;
            if (gn < Nc) C[(size_t)gr * Nc + gn] = acc[i][j] + bias[gn];
        }
    }
}

// fp16 output, row-scaled by dis[gr] (staged aggregation operand)
__global__ __launch_bounds__(256) void k_gemm_h(const float* __restrict__ A,
                                                const float* __restrict__ Bw,
                                                __half* __restrict__ C,
                                                int M, int K, int Nc,
                                                const float* __restrict__ dis) {
    __shared__ float As[16][65];
    __shared__ float Bs[16][65];
    int bm = blockIdx.x * 64;
    int bn = blockIdx.y * 64;
    int tid = threadIdx.x;
    int tx = tid & 15, ty = tid >> 4;
    float acc[4][4] = {};
    for (int k0 = 0; k0 < K; k0 += 16) {
        #pragma unroll
        for (int p = 0; p < 4; p++) {
            int r = (tid >> 4) + p * 16;
            int c = tid & 15;
            int gr = bm + r;
            As[c][r] = (gr < M) ? A[(size_t)gr * K + k0 + c] : 0.f;
        }
        #pragma unroll
        for (int p = 0; p < 4; p++) {
            int kk = (tid >> 6) + p * 4;
            int n  = tid & 63;
            int gn = bn + n;
            Bs[kk][n] = (gn < Nc) ? Bw[(size_t)(k0 + kk) * Nc + gn] : 0.f;
        }
        __syncthreads();
        #pragma unroll
        for (int kk = 0; kk < 16; kk++) {
            float a0[4], b0[4];
            #pragma unroll
            for (int i = 0; i < 4; i++) a0[i] = As[kk][ty * 4 + i];
            #pragma unroll
            for (int j = 0; j < 4; j++) b0[j] = Bs[kk][tx * 4 + j];
            #pragma unroll
            for (int i = 0; i < 4; i++)
                #pragma unroll
                for (int j = 0; j < 4; j++) acc[i][j] += a0[i] * b0[j];
        }
        __syncthreads();
    }
    #pragma unroll
    for (int i = 0; i < 4; i++) {
        int gr = bm + ty * 4 + i;
        if (gr >= M) continue;
        float ds = dis[gr];
        int gn0 = bn + tx * 4;
        if (gn0 < Nc) {  // Nc % 4 == 0 -> whole half4 in or out
            __half2 h01 = __floats2half2_rn(ds * acc[i][0], ds * acc[i][1]);
            __half2 h23 = __floats2half2_rn(ds * acc[i][2], ds * acc[i][3]);
            union { __half2 h; unsigned u; } a, b;
            a.h = h01; b.h = h23;
            *(uint2*)&C[(size_t)gr * Nc + gn0] = make_uint2(a.u, b.u);
        }
    }
}

// layer-1 staging: Hs = fp16(dis[i] * x[i][:])  (d = 128)
__global__ void k_scale_h(const float4* __restrict__ X, const float* __restrict__ dis,
                          uint2* __restrict__ out) {
    int t = blockIdx.x * blockDim.x + threadIdx.x;
    if (t >= NN * 32) return;
    int row = t >> 5;  // 32 float4 per row
    float ds = dis[row];
    float4 v = X[t];
    union { __half2 h; unsigned u; } a, b;
    a.h = __floats2half2_rn(ds * v.x, ds * v.y);
    b.h = __floats2half2_rn(ds * v.z, ds * v.w);
    out[t] = make_uint2(a.u, b.u);
}

// ---------------------------------------------------------------- aggregation
// Hs rows are fp16, pre-scaled by dis[src]. TPN = d/8 threads/node, 16B/thread.
// out[i][:] = dis[i] * (sum_e Hs[col[e]][:] + Hs[i][:]) + bias

__device__ __forceinline__ void acc_row(float* acc, const uint4& r) {
    const __half2* hp = (const __half2*)&r;
    #pragma unroll
    for (int k = 0; k < 4; k++) {
        float2 f2 = __half22float2(hp[k]);
        acc[2 * k]     += f2.x;
        acc[2 * k + 1] += f2.y;
    }
}

template<int TPN>
__global__ __launch_bounds__(256) void k_agg_h(const uint4* __restrict__ Hs,
                                               float4* __restrict__ out,
                                               const int* __restrict__ rowptr,
                                               const int* __restrict__ degcnt,
                                               const int* __restrict__ colv,
                                               const float* __restrict__ dis,
                                               const float* __restrict__ bias) {
    constexpr int G = 256 / TPN;
    int g    = threadIdx.x / TPN;
    int lane = threadIdx.x % TPN;
    int i = blockIdx.x * G + g;
    if (i >= NN) return;
    int beg = rowptr[i];
    int cnt = degcnt[i];
    const uint4* base = Hs + lane;
    float acc[8] = {};
    int e = 0;
    for (; e + 8 <= cnt; e += 8) {
        int c[8];
        #pragma unroll
        for (int j = 0; j < 8; j++) c[j] = colv[beg + e + j];
        uint4 r[8];
        #pragma unroll
        for (int j = 0; j < 8; j++) r[j] = base[(size_t)c[j] * TPN];
        #pragma unroll
        for (int j = 0; j < 8; j++) acc_row(acc, r[j]);
    }
    for (; e < cnt; e++) {
        int c = colv[beg + e];
        uint4 r = base[(size_t)c * TPN];
        acc_row(acc, r);
    }
    uint4 rs = base[(size_t)i * TPN];  // self-loop
    acc_row(acc, rs);
    float ds = dis[i];
    float o[8];
    #pragma unroll
    for (int k = 0; k < 8; k++) o[k] = ds * acc[k];
    if (bias) {
        float4 b0 = ((const float4*)bias)[lane * 2];
        float4 b1 = ((const float4*)bias)[lane * 2 + 1];
        o[0] += b0.x; o[1] += b0.y; o[2] += b0.z; o[3] += b0.w;
        o[4] += b1.x; o[5] += b1.y; o[6] += b1.z; o[7] += b1.w;
    }
    size_t ob = (size_t)i * (2 * TPN) + lane * 2;
    out[ob]     = make_float4(o[0], o[1], o[2], o[3]);
    out[ob + 1] = make_float4(o[4], o[5], o[6], o[7]);
}

// ---------------------------------------------------------------- BatchNorm

__global__ __launch_bounds__(256) void k_bnstat(const float* __restrict__ Xc,
                                                float* __restrict__ bn, int d,
                                                int rows_per_blk) {
    int rpt = 256 / d;
    int f  = threadIdx.x & (d - 1);
    int r0 = threadIdx.x / d;
    int base = blockIdx.x * rows_per_blk;
    float s = 0.f, s2 = 0.f;
    for (int r = r0; r < rows_per_blk; r += rpt) {
        int i = base + r;
        if (i < NN) {
            float v = Xc[(size_t)i * d + f];
            s += v; s2 += v * v;
        }
    }
    __shared__ float ls[256], ls2[256];
    ls[threadIdx.x] = s; ls2[threadIdx.x] = s2;
    __syncthreads();
    if (threadIdx.x < d) {
        float a = 0.f, b = 0.f;
        for (int g = 0; g < rpt; g++) { a += ls[g * d + threadIdx.x]; b += ls2[g * d + threadIdx.x]; }
        atomicAdd(&bn[threadIdx.x], a);
        atomicAdd(&bn[d + threadIdx.x], b);
    }
}

__global__ void k_bnfin(const float* __restrict__ bn, const float* __restrict__ g,
                        const float* __restrict__ be, float* __restrict__ AB, int d) {
    int f = threadIdx.x;
    if (f < d) {
        float mu  = bn[f] / (float)NN;
        float var = bn[d + f] / (float)NN - mu * mu;
        var = fmaxf(var, 0.f);
        float inv = rsqrtf(var + EPSB);
        float a = g[f] * inv;
        AB[f]     = a;
        AB[d + f] = be[f] - mu * a;
    }
}

__global__ void k_norm(float* __restrict__ X, const float* __restrict__ AB,
                       int d, int total) {
    int idx = blockIdx.x * blockDim.x + threadIdx.x;
    if (idx < total) {
        int f = idx & (d - 1);
        float v = X[idx] * AB[f] + AB[d + f];
        X[idx] = fmaxf(v, 0.f);
    }
}

// ---------------------------------------------------------------- final edge MLP

__global__ __launch_bounds__(256) void k_edge(const float4* __restrict__ X,
                                              const int* __restrict__ src,
                                              const int* __restrict__ dst,
                                              const float* __restrict__ fcw,
                                              const float* __restrict__ fcb,
                                              float* __restrict__ out) {
    int lane = threadIdx.x & 7;
    size_t t = (size_t)blockIdx.x * 256 + threadIdx.x;
    int eid = (int)(t >> 3);
    if (eid >= EE) return;
    int s = src[eid], d = dst[eid];
    float4 a = X[(size_t)s * 8 + lane];
    float4 b = X[(size_t)d * 8 + lane];
    float4 w = ((const float4*)fcw)[lane];
    float v = a.x * b.x * w.x + a.y * b.y * w.y + a.z * b.z * w.z + a.w * b.w * w.w;
    v += __shfl_xor(v, 1, 8);
    v += __shfl_xor(v, 2, 8);
    v += __shfl_xor(v, 4, 8);
    if (lane == 0) out[eid] = 1.f / (1.f + expf(-(v + fcb[0])));
}

// ---------------------------------------------------------------- launch

static inline void launch_agg(int d, const __half* Hs, float* out,
                              const int* rowptr, const int* degcnt,
                              const int* colv, const float* dis,
                              const float* bias, hipStream_t stream) {
    if (d == 128) {
        constexpr int TPN = 16, G = 256 / TPN;
        k_agg_h<TPN><<<(NN + G - 1) / G, 256, 0, stream>>>(
            (const uint4*)Hs, (float4*)out, rowptr, degcnt, colv, dis, bias);
    } else if (d == 64) {
        constexpr int TPN = 8, G = 256 / TPN;
        k_agg_h<TPN><<<(NN + G - 1) / G, 256, 0, stream>>>(
            (const uint4*)Hs, (float4*)out, rowptr, degcnt, colv, dis, bias);
    } else { // d == 32
        constexpr int TPN = 4, G = 256 / TPN;
        k_agg_h<TPN><<<(NN + G - 1) / G, 256, 0, stream>>>(
            (const uint4*)Hs, (float4*)out, rowptr, degcnt, colv, dis, bias);
    }
}

static inline void run_bn(float* X, int d, const float* g, const float* be,
                          float* bn, float* bnAB, hipStream_t stream) {
    hipMemsetAsync(bn, 0, (size_t)2 * d * 4, stream);
    k_bnstat<<<(NN + 511) / 512, 256, 0, stream>>>(X, bn, d, 512);
    k_bnfin<<<1, 256, 0, stream>>>(bn, g, be, bnAB, d);
    int total = NN * d;
    k_norm<<<(total + 255) / 256, 256, 0, stream>>>(X, bnAB, d, total);
}

extern "C" void kernel_launch(void* const* d_in, const int* in_sizes, int n_in,
                              void* d_out, int out_size, void* d_ws, size_t ws_size,
                              hipStream_t stream) {
    const float* x0 = (const float*)d_in[0];
    const int* ei   = (const int*)d_in[1];
    const int* srcv = ei;
    const int* dstv = ei + EE;
    const float *W[5], *bp[5], *gp[5], *bep[5];
    int idx = 2;
    for (int l = 0; l < 5; l++) {
        W[l]   = (const float*)d_in[idx++];
        bp[l]  = (const float*)d_in[idx++];
        gp[l]  = (const float*)d_in[idx++];
        bep[l] = (const float*)d_in[idx++];
    }
    const float* fcw = (const float*)d_in[22];
    const float* fcb = (const float*)d_in[23];

    char* ws = (char*)d_ws;
    size_t off = 0;
    auto alloc = [&](size_t bytes) -> void* {
        void* p = ws + off;
        off = (off + bytes + 255) & ~(size_t)255;
        return p;
    };
    float*  bufA   = (float*) alloc((size_t)NN * 256 * 4);    // up to d=256
    float*  bufB   = (float*) alloc((size_t)NN * 128 * 4);    // up to d=128
    __half* Hh     = (__half*)alloc((size_t)NN * 128 * 2);    // staged fp16
    uint2*  barr   = (uint2*) alloc((size_t)NB * BCAP * 8);   // bucketed edges (32MB)
    int*    colv   = (int*)   alloc((size_t)EE * 4);
    int*    rowptr = (int*)   alloc((size_t)NN * 4);
    int*    degcnt = (int*)   alloc((size_t)NN * 4);
    float*  dis    = (float*) alloc((size_t)NN * 4);
    int*    bcur   = (int*)   alloc((size_t)NB * 4);
    int*    scnblk = (int*)   alloc(4096);
    float*  bn     = (float*) alloc(512 * 4);
    float*  bnAB   = (float*) alloc(512 * 4);

    // ---- CSR build (binned counting sort)
    hipMemsetAsync(bcur, 0, (size_t)NB * 4, stream);
    k_bscat<<<(EE + 4095) / 4096, 256, 0, stream>>>(srcv, dstv, bcur, barr);
    k_bdeg<<<NB, 1024, 0, stream>>>(bcur, barr, degcnt);
    k_deg<<<(NN + 255) / 256, 256, 0, stream>>>(degcnt, dis);
    int nScanBlk = (NN + 1023) / 1024;  // 98
    k_scan_block<<<nScanBlk, 1024, 0, stream>>>(degcnt, rowptr, scnblk, NN);
    k_scan_top<<<1, 64, 0, stream>>>(scnblk, nScanBlk);
    k_scan_add<<<nScanBlk, 1024, 0, stream>>>(rowptr, scnblk, NN);
    k_place<<<NB, 1024, 0, stream>>>(bcur, barr, rowptr, colv);

    // ---- layer 0: gemm_h(x0,W0)->Hh ; agg->bufA (+b0) ; BN(bufA,128)
    {
        dim3 grid((NN + 63) / 64, 128 / 64);
        k_gemm_h<<<grid, 256, 0, stream>>>(x0, W[0], Hh, NN, 128, 128, dis);
        launch_agg(128, Hh, bufA, rowptr, degcnt, colv, dis, bp[0], stream);
        run_bn(bufA, 128, gp[0], bep[0], bn, bnAB, stream);
    }
    // ---- layer 1 (agg first): scale_h(bufA)->Hh ; agg->bufB ; gemm_f(bufB,W1)+b1->bufA ; BN(bufA,256)
    {
        k_scale_h<<<(NN * 32 + 255) / 256, 256, 0, stream>>>((const float4*)bufA, dis, (uint2*)Hh);
        launch_agg(128, Hh, bufB, rowptr, degcnt, colv, dis, nullptr, stream);
        dim3 grid((NN + 63) / 64, 256 / 64);
        k_gemm_f<<<grid, 256, 0, stream>>>(bufB, W[1], bufA, NN, 128, 256, bp[1]);
        run_bn(bufA, 256, gp[1], bep[1], bn, bnAB, stream);
    }
    // ---- layer 2: gemm_h(bufA,W2)->Hh ; agg->bufB (+b2) ; BN(bufB,128)
    {
        dim3 grid((NN + 63) / 64, 128 / 64);
        k_gemm_h<<<grid, 256, 0, stream>>>(bufA, W[2], Hh, NN, 256, 128, dis);
        launch_agg(128, Hh, bufB, rowptr, degcnt, colv, dis, bp[2], stream);
        run_bn(bufB, 128, gp[2], bep[2], bn, bnAB, stream);
    }
    // ---- layer 3: gemm_h(bufB,W3)->Hh ; agg->bufA (+b3) ; BN(bufA,64)
    {
        dim3 grid((NN + 63) / 64, 64 / 64);
        k_gemm_h<<<grid, 256, 0, stream>>>(bufB, W[3], Hh, NN, 128, 64, dis);
        launch_agg(64, Hh, bufA, rowptr, degcnt, colv, dis, bp[3], stream);
        run_bn(bufA, 64, gp[3], bep[3], bn, bnAB, stream);
    }
    // ---- layer 4: gemm_h(bufA,W4)->Hh ; agg->bufB (+b4) ; BN(bufB,32)
    {
        dim3 grid((NN + 63) / 64, 1);
        k_gemm_h<<<grid, 256, 0, stream>>>(bufA, W[4], Hh, NN, 64, 32, dis);
        launch_agg(32, Hh, bufB, rowptr, degcnt, colv, dis, bp[4], stream);
        run_bn(bufB, 32, gp[4], bep[4], bn, bnAB, stream);
    }

    size_t edgeThreads = (size_t)EE * 8;
    k_edge<<<(unsigned)((edgeThreads + 255) / 256), 256, 0, stream>>>(
        (const float4*)bufB, srcv, dstv, fcw, fcb, (float*)d_out);
}

// Round 5
// 1279.721 us; speedup vs baseline: 2.9074x; 1.3400x over previous
//
#include <hip/hip_runtime.h>
#include <hip/hip_fp16.h>
#include <cstddef>

#define NN 100000
#define EE 3200000
#define EPSB 1e-5f
#define NB 391      // buckets = ceil(NN/256)
#define BCAP 10240  // per-bucket edge capacity

typedef _Float16 half8 __attribute__((ext_vector_type(8)));
typedef float floatx4 __attribute__((ext_vector_type(4)));

// ---------------------------------------------------------------- CSR build

__global__ __launch_bounds__(256) void k_bscat(const int* __restrict__ src,
                                               const int* __restrict__ dst,
                                               int* __restrict__ bcur,
                                               uint2* __restrict__ barr) {
    __shared__ int hist[NB];
    __shared__ int base[NB];
    int tid = threadIdx.x;
    for (int b = tid; b < NB; b += 256) hist[b] = 0;
    __syncthreads();
    int e0 = blockIdx.x * 4096;
    int d[16], s[16];
    #pragma unroll
    for (int j = 0; j < 16; j++) {
        int e = e0 + j * 256 + tid;
        if (e < EE) {
            d[j] = dst[e];
            s[j] = src[e];
            atomicAdd(&hist[d[j] >> 8], 1);
        } else d[j] = -1;
    }
    __syncthreads();
    for (int b = tid; b < NB; b += 256) {
        int c = hist[b];
        base[b] = (c > 0) ? atomicAdd(&bcur[b], c) : 0;
        hist[b] = 0;
    }
    __syncthreads();
    #pragma unroll
    for (int j = 0; j < 16; j++) {
        if (d[j] >= 0) {
            int b = d[j] >> 8;
            int r = atomicAdd(&hist[b], 1);
            barr[(size_t)b * BCAP + base[b] + r] = make_uint2((unsigned)s[j], (unsigned)d[j]);
        }
    }
}

__global__ __launch_bounds__(1024) void k_bdeg(const int* __restrict__ bcur,
                                               const uint2* __restrict__ barr,
                                               int* __restrict__ degcnt) {
    __shared__ int h[256];
    int b = blockIdx.x;
    if (threadIdx.x < 256) h[threadIdx.x] = 0;
    __syncthreads();
    int cnt = bcur[b];
    const uint2* p = barr + (size_t)b * BCAP;
    for (int t = threadIdx.x; t < cnt; t += 1024)
        atomicAdd(&h[p[t].y & 255], 1);
    __syncthreads();
    if (threadIdx.x < 256) {
        int node = (b << 8) + threadIdx.x;
        if (node < NN) degcnt[node] = h[threadIdx.x];
    }
}

__global__ __launch_bounds__(1024) void k_place(const int* __restrict__ bcur,
                                                const uint2* __restrict__ barr,
                                                const int* __restrict__ rowptr,
                                                int* __restrict__ col) {
    __shared__ int cur[256];
    int b = blockIdx.x;
    if (threadIdx.x < 256) {
        int node = (b << 8) + threadIdx.x;
        cur[threadIdx.x] = (node < NN) ? rowptr[node] : 0;
    }
    __syncthreads();
    int cnt = bcur[b];
    const uint2* p = barr + (size_t)b * BCAP;
    for (int t = threadIdx.x; t < cnt; t += 1024) {
        uint2 e = p[t];
        int pos = atomicAdd(&cur[e.y & 255], 1);
        col[pos] = (int)e.x;
    }
}

__global__ void k_deg(const int* __restrict__ degcnt, float* __restrict__ dis) {
    int i = blockIdx.x * blockDim.x + threadIdx.x;
    if (i < NN) {
        float d = (float)degcnt[i] + 1.0f;
        dis[i] = rsqrtf(d);
    }
}

__global__ void k_scan_block(const int* __restrict__ in, int* __restrict__ out,
                             int* __restrict__ blksum, int n) {
    __shared__ int s[1024];
    int i = blockIdx.x * 1024 + threadIdx.x;
    int v = (i < n) ? in[i] : 0;
    s[threadIdx.x] = v;
    __syncthreads();
    for (int off = 1; off < 1024; off <<= 1) {
        int t = (threadIdx.x >= off) ? s[threadIdx.x - off] : 0;
        __syncthreads();
        s[threadIdx.x] += t;
        __syncthreads();
    }
    if (i < n) out[i] = s[threadIdx.x] - v;  // exclusive
    if (threadIdx.x == 1023) blksum[blockIdx.x] = s[1023];
}

__global__ void k_scan_top(int* __restrict__ blksum, int nb) {
    if (threadIdx.x == 0) {
        int acc = 0;
        for (int b = 0; b < nb; b++) { int v = blksum[b]; blksum[b] = acc; acc += v; }
    }
}

__global__ void k_scan_add(int* __restrict__ out, const int* __restrict__ blksum, int n) {
    int i = blockIdx.x * 1024 + threadIdx.x;
    if (i < n) out[i] += blksum[blockIdx.x];
}

// ---------------------------------------------------------------- casts / packing

// fp32 -> fp16 elementwise (x0 cast), 4 elems/thread
__global__ void k_f2h(const float4* __restrict__ in, uint2* __restrict__ out, int n4) {
    int t = blockIdx.x * blockDim.x + threadIdx.x;
    if (t >= n4) return;
    float4 v = in[t];
    union { __half2 h; unsigned u; } a, b;
    a.h = __floats2half2_rn(v.x, v.y);
    b.h = __floats2half2_rn(v.z, v.w);
    out[t] = make_uint2(a.u, b.u);
}

// W[K][N] fp32 -> Wp[N][K] fp16 (transposed pack for MFMA B-frag reads)
__global__ void k_wpack(const float* __restrict__ W, __half* __restrict__ Wp,
                        int K, int N) {
    int t = blockIdx.x * blockDim.x + threadIdx.x;
    if (t < K * N) {
        int k = t / N, n = t - k * N;
        Wp[(size_t)n * K + k] = __float2half(W[t]);
    }
}

// ---------------------------------------------------------------- MFMA GEMM
// C[M,N] = A[M,K] @ W[K,N], A fp16 row-major, W packed [N][K] fp16.
// Block: 256 thr (4 waves), 128 rows x (NT*16) cols; BK=32.
// OUT16: C fp16 = dis[row] * acc   (staged agg operand)
// else : C fp32 = acc + bias[col]

template<int NT, bool OUT16>
__global__ __launch_bounds__(256) void k_mgemm(const __half* __restrict__ A,
                                               const __half* __restrict__ Wp,
                                               void* __restrict__ Cv,
                                               int M, int K, int N,
                                               const float* __restrict__ dis,
                                               const float* __restrict__ bias) {
    constexpr int TN = NT * 16;
    __shared__ __half Ash[128][40];
    __shared__ __half Bsh[TN][40];
    int tid  = threadIdx.x;
    int wave = tid >> 6;
    int lane = tid & 63;
    int quad = lane >> 4;
    int l16  = lane & 15;
    int bm = blockIdx.x * 128;
    int bn = blockIdx.y * TN;

    floatx4 acc[2][NT];
    #pragma unroll
    for (int mt = 0; mt < 2; mt++)
        #pragma unroll
        for (int nt = 0; nt < NT; nt++)
            acc[mt][nt] = (floatx4){0.f, 0.f, 0.f, 0.f};

    for (int k0 = 0; k0 < K; k0 += 32) {
        // stage A: 128 rows x 32 halves = 512 uint4
        #pragma unroll
        for (int it = 0; it < 2; it++) {
            int u = tid + it * 256;
            int row = u >> 2, seg = u & 3;
            int grow = bm + row;
            uint4 v = make_uint4(0, 0, 0, 0);
            if (grow < M) v = *(const uint4*)&A[(size_t)grow * K + k0 + seg * 8];
            *(uint4*)&Ash[row][seg * 8] = v;
        }
        // stage B: TN rows x 32 halves = TN*4 uint4
        if (tid < TN * 4) {
            int n = tid >> 2, seg = tid & 3;
            uint4 v = *(const uint4*)&Wp[(size_t)(bn + n) * K + k0 + seg * 8];
            *(uint4*)&Bsh[n][seg * 8] = v;
        }
        __syncthreads();
        half8 a[2], b[NT];
        #pragma unroll
        for (int mt = 0; mt < 2; mt++)
            a[mt] = *(const half8*)&Ash[wave * 32 + mt * 16 + l16][quad * 8];
        #pragma unroll
        for (int nt = 0; nt < NT; nt++)
            b[nt] = *(const half8*)&Bsh[nt * 16 + l16][quad * 8];
        #pragma unroll
        for (int mt = 0; mt < 2; mt++)
            #pragma unroll
            for (int nt = 0; nt < NT; nt++)
                acc[mt][nt] = __builtin_amdgcn_mfma_f32_16x16x32_f16(
                    a[mt], b[nt], acc[mt][nt], 0, 0, 0);
        __syncthreads();
    }

    // epilogue: D[row=(quad*4+r)][col=l16] per 16x16 tile
    #pragma unroll
    for (int mt = 0; mt < 2; mt++) {
        #pragma unroll
        for (int r = 0; r < 4; r++) {
            int grow = bm + wave * 32 + mt * 16 + quad * 4 + r;
            if (grow >= M) continue;
            if (OUT16) {
                float ds = dis[grow];
                __half* C = (__half*)Cv;
                #pragma unroll
                for (int nt = 0; nt < NT; nt++) {
                    int gcol = bn + nt * 16 + l16;
                    C[(size_t)grow * N + gcol] = __float2half(ds * acc[mt][nt][r]);
                }
            } else {
                float* C = (float*)Cv;
                #pragma unroll
                for (int nt = 0; nt < NT; nt++) {
                    int gcol = bn + nt * 16 + l16;
                    C[(size_t)grow * N + gcol] = acc[mt][nt][r] + bias[gcol];
                }
            }
        }
    }
}

// layer-1 staging: Hh = fp16(dis[i] * act16[i][:]), d=128 (16 uint4/row)
__global__ void k_scale16(const uint4* __restrict__ X, const float* __restrict__ dis,
                          uint4* __restrict__ out) {
    int t = blockIdx.x * blockDim.x + threadIdx.x;
    if (t >= NN * 16) return;
    int row = t >> 4;
    float ds = dis[row];
    uint4 v = X[t];
    const __half2* hp = (const __half2*)&v;
    uint4 o;
    __half2* op = (__half2*)&o;
    #pragma unroll
    for (int k = 0; k < 4; k++) {
        float2 f = __half22float2(hp[k]);
        op[k] = __floats2half2_rn(ds * f.x, ds * f.y);
    }
    out[t] = o;
}

// ---------------------------------------------------------------- aggregation
// Hs fp16 rows pre-scaled by dis[src]. TPN = d/8 threads/node.
// out[i] = dis[i]*(sum_e Hs[col[e]] + Hs[i]) + bias ; fp32 or fp16 out.

__device__ __forceinline__ void acc_row(float* acc, const uint4& r) {
    const __half2* hp = (const __half2*)&r;
    #pragma unroll
    for (int k = 0; k < 4; k++) {
        float2 f2 = __half22float2(hp[k]);
        acc[2 * k]     += f2.x;
        acc[2 * k + 1] += f2.y;
    }
}

template<int TPN, bool OUT16>
__global__ __launch_bounds__(256) void k_agg_h(const uint4* __restrict__ Hs,
                                               void* __restrict__ outv,
                                               const int* __restrict__ rowptr,
                                               const int* __restrict__ degcnt,
                                               const int* __restrict__ colv,
                                               const float* __restrict__ dis,
                                               const float* __restrict__ bias) {
    constexpr int G = 256 / TPN;
    int g    = threadIdx.x / TPN;
    int lane = threadIdx.x % TPN;
    int i = blockIdx.x * G + g;
    if (i >= NN) return;
    int beg = rowptr[i];
    int cnt = degcnt[i];
    const uint4* base = Hs + lane;
    float acc[8] = {};
    int e = 0;
    for (; e + 8 <= cnt; e += 8) {
        int c[8];
        #pragma unroll
        for (int j = 0; j < 8; j++) c[j] = colv[beg + e + j];
        uint4 r[8];
        #pragma unroll
        for (int j = 0; j < 8; j++) r[j] = base[(size_t)c[j] * TPN];
        #pragma unroll
        for (int j = 0; j < 8; j++) acc_row(acc, r[j]);
    }
    for (; e < cnt; e++) {
        int c = colv[beg + e];
        uint4 r = base[(size_t)c * TPN];
        acc_row(acc, r);
    }
    uint4 rs = base[(size_t)i * TPN];  // self-loop
    acc_row(acc, rs);
    float ds = dis[i];
    float o[8];
    #pragma unroll
    for (int k = 0; k < 8; k++) o[k] = ds * acc[k];
    if (bias) {
        float4 b0 = ((const float4*)bias)[lane * 2];
        float4 b1 = ((const float4*)bias)[lane * 2 + 1];
        o[0] += b0.x; o[1] += b0.y; o[2] += b0.z; o[3] += b0.w;
        o[4] += b1.x; o[5] += b1.y; o[6] += b1.z; o[7] += b1.w;
    }
    if (OUT16) {
        uint4 ov;
        __half2* op = (__half2*)&ov;
        #pragma unroll
        for (int k = 0; k < 4; k++) op[k] = __floats2half2_rn(o[2 * k], o[2 * k + 1]);
        ((uint4*)outv)[(size_t)i * TPN + lane] = ov;
    } else {
        float4* out = (float4*)outv;
        size_t ob = (size_t)i * (2 * TPN) + lane * 2;
        out[ob]     = make_float4(o[0], o[1], o[2], o[3]);
        out[ob + 1] = make_float4(o[4], o[5], o[6], o[7]);
    }
}

// ---------------------------------------------------------------- BatchNorm

__global__ __launch_bounds__(256) void k_bnstat(const float* __restrict__ Xc,
                                                float* __restrict__ bn, int d,
                                                int rows_per_blk) {
    int rpt = 256 / d;
    int f  = threadIdx.x & (d - 1);
    int r0 = threadIdx.x / d;
    int base = blockIdx.x * rows_per_blk;
    float s = 0.f, s2 = 0.f;
    for (int r = r0; r < rows_per_blk; r += rpt) {
        int i = base + r;
        if (i < NN) {
            float v = Xc[(size_t)i * d + f];
            s += v; s2 += v * v;
        }
    }
    __shared__ float ls[256], ls2[256];
    ls[threadIdx.x] = s; ls2[threadIdx.x] = s2;
    __syncthreads();
    if (threadIdx.x < d) {
        float a = 0.f, b = 0.f;
        for (int g = 0; g < rpt; g++) { a += ls[g * d + threadIdx.x]; b += ls2[g * d + threadIdx.x]; }
        atomicAdd(&bn[threadIdx.x], a);
        atomicAdd(&bn[d + threadIdx.x], b);
    }
}

__global__ void k_bnfin(const float* __restrict__ bn, const float* __restrict__ g,
                        const float* __restrict__ be, float* __restrict__ AB, int d) {
    int f = threadIdx.x;
    if (f < d) {
        float mu  = bn[f] / (float)NN;
        float var = bn[d + f] / (float)NN - mu * mu;
        var = fmaxf(var, 0.f);
        float inv = rsqrtf(var + EPSB);
        float a = g[f] * inv;
        AB[f]     = a;
        AB[d + f] = be[f] - mu * a;
    }
}

// BN apply + ReLU, fp32 in -> fp16 out. 4 elems/thread.
__global__ void k_norm16(const float4* __restrict__ X, const float* __restrict__ AB,
                         uint2* __restrict__ Y, int d, int total4) {
    int t = blockIdx.x * blockDim.x + threadIdx.x;
    if (t >= total4) return;
    int f0 = (t * 4) & (d - 1);
    float4 v = X[t];
    float a0 = AB[f0],     a1 = AB[f0 + 1], a2 = AB[f0 + 2], a3 = AB[f0 + 3];
    float c0 = AB[d + f0], c1 = AB[d + f0 + 1], c2 = AB[d + f0 + 2], c3 = AB[d + f0 + 3];
    float o0 = fmaxf(v.x * a0 + c0, 0.f);
    float o1 = fmaxf(v.y * a1 + c1, 0.f);
    float o2 = fmaxf(v.z * a2 + c2, 0.f);
    float o3 = fmaxf(v.w * a3 + c3, 0.f);
    union { __half2 h; unsigned u; } p, q;
    p.h = __floats2half2_rn(o0, o1);
    q.h = __floats2half2_rn(o2, o3);
    Y[t] = make_uint2(p.u, q.u);
}

// ---------------------------------------------------------------- final edge MLP
// fp16 activations d=32 -> 4 uint4/row; 4 lanes/edge.

__global__ __launch_bounds__(256) void k_edge16(const uint4* __restrict__ X,
                                                const int* __restrict__ src,
                                                const int* __restrict__ dst,
                                                const float* __restrict__ fcw,
                                                const float* __restrict__ fcb,
                                                float* __restrict__ out) {
    int lane = threadIdx.x & 3;
    size_t t = (size_t)blockIdx.x * 256 + threadIdx.x;
    int eid = (int)(t >> 2);
    if (eid >= EE) return;
    int s = src[eid], d = dst[eid];
    uint4 av = X[(size_t)s * 4 + lane];
    uint4 bv = X[(size_t)d * 4 + lane];
    const __half2* ap = (const __half2*)&av;
    const __half2* bp2 = (const __half2*)&bv;
    float v = 0.f;
    #pragma unroll
    for (int k = 0; k < 4; k++) {
        float2 fa = __half22float2(ap[k]);
        float2 fb = __half22float2(bp2[k]);
        float w0 = fcw[lane * 8 + 2 * k];
        float w1 = fcw[lane * 8 + 2 * k + 1];
        v += fa.x * fb.x * w0 + fa.y * fb.y * w1;
    }
    v += __shfl_xor(v, 1, 4);
    v += __shfl_xor(v, 2, 4);
    if (lane == 0) out[eid] = 1.f / (1.f + expf(-(v + fcb[0])));
}

// ---------------------------------------------------------------- launch

static inline void launch_agg_f(int d, const __half* Hs, float* out,
                                const int* rowptr, const int* degcnt,
                                const int* colv, const float* dis,
                                const float* bias, hipStream_t stream) {
    if (d == 128) {
        constexpr int TPN = 16, G = 256 / TPN;
        k_agg_h<TPN, false><<<(NN + G - 1) / G, 256, 0, stream>>>(
            (const uint4*)Hs, out, rowptr, degcnt, colv, dis, bias);
    } else if (d == 64) {
        constexpr int TPN = 8, G = 256 / TPN;
        k_agg_h<TPN, false><<<(NN + G - 1) / G, 256, 0, stream>>>(
            (const uint4*)Hs, out, rowptr, degcnt, colv, dis, bias);
    } else { // d == 32
        constexpr int TPN = 4, G = 256 / TPN;
        k_agg_h<TPN, false><<<(NN + G - 1) / G, 256, 0, stream>>>(
            (const uint4*)Hs, out, rowptr, degcnt, colv, dis, bias);
    }
}

static inline void run_bn(const float* X, __half* Y16, int d, const float* g,
                          const float* be, float* bn, float* bnAB,
                          hipStream_t stream) {
    hipMemsetAsync(bn, 0, (size_t)2 * d * 4, stream);
    k_bnstat<<<(NN + 511) / 512, 256, 0, stream>>>(X, bn, d, 512);
    k_bnfin<<<1, 256, 0, stream>>>(bn, g, be, bnAB, d);
    int total4 = NN * d / 4;
    k_norm16<<<(total4 + 255) / 256, 256, 0, stream>>>(
        (const float4*)X, bnAB, (uint2*)Y16, d, total4);
}

extern "C" void kernel_launch(void* const* d_in, const int* in_sizes, int n_in,
                              void* d_out, int out_size, void* d_ws, size_t ws_size,
                              hipStream_t stream) {
    const float* x0 = (const float*)d_in[0];
    const int* ei   = (const int*)d_in[1];
    const int* srcv = ei;
    const int* dstv = ei + EE;
    const float *W[5], *bp[5], *gp[5], *bep[5];
    int idx = 2;
    for (int l = 0; l < 5; l++) {
        W[l]   = (const float*)d_in[idx++];
        bp[l]  = (const float*)d_in[idx++];
        gp[l]  = (const float*)d_in[idx++];
        bep[l] = (const float*)d_in[idx++];
    }
    const float* fcw = (const float*)d_in[22];
    const float* fcb = (const float*)d_in[23];

    char* ws = (char*)d_ws;
    size_t off = 0;
    auto alloc = [&](size_t bytes) -> void* {
        void* p = ws + off;
        off = (off + bytes + 255) & ~(size_t)255;
        return p;
    };
    float*  bufA   = (float*) alloc((size_t)NN * 256 * 4);    // fp32 BN input
    __half* act16  = (__half*)alloc((size_t)NN * 256 * 2);    // fp16 activations
    __half* x16    = (__half*)alloc((size_t)NN * 128 * 2);    // fp16 cast of x0
    __half* Hh     = (__half*)alloc((size_t)NN * 128 * 2);    // staged agg operand
    uint2*  barr   = (uint2*) alloc((size_t)NB * BCAP * 8);
    int*    colv   = (int*)   alloc((size_t)EE * 4);
    int*    rowptr = (int*)   alloc((size_t)NN * 4);
    int*    degcnt = (int*)   alloc((size_t)NN * 4);
    float*  dis    = (float*) alloc((size_t)NN * 4);
    int*    bcur   = (int*)   alloc((size_t)NB * 4);
    int*    scnblk = (int*)   alloc(4096);
    float*  bn     = (float*) alloc(512 * 4);
    float*  bnAB   = (float*) alloc(512 * 4);
    __half* Wp[5];
    const int dims[6] = {128, 128, 256, 128, 64, 32};
    for (int l = 0; l < 5; l++) Wp[l] = (__half*)alloc((size_t)dims[l] * dims[l + 1] * 2);

    // ---- CSR build (binned counting sort)
    hipMemsetAsync(bcur, 0, (size_t)NB * 4, stream);
    k_bscat<<<(EE + 4095) / 4096, 256, 0, stream>>>(srcv, dstv, bcur, barr);
    k_bdeg<<<NB, 1024, 0, stream>>>(bcur, barr, degcnt);
    k_deg<<<(NN + 255) / 256, 256, 0, stream>>>(degcnt, dis);
    int nScanBlk = (NN + 1023) / 1024;
    k_scan_block<<<nScanBlk, 1024, 0, stream>>>(degcnt, rowptr, scnblk, NN);
    k_scan_top<<<1, 64, 0, stream>>>(scnblk, nScanBlk);
    k_scan_add<<<nScanBlk, 1024, 0, stream>>>(rowptr, scnblk, NN);
    k_place<<<NB, 1024, 0, stream>>>(bcur, barr, rowptr, colv);

    // ---- casts / weight packs
    k_f2h<<<(NN * 128 / 4 + 255) / 256, 256, 0, stream>>>(
        (const float4*)x0, (uint2*)x16, NN * 128 / 4);
    for (int l = 0; l < 5; l++) {
        int kn = dims[l] * dims[l + 1];
        k_wpack<<<(kn + 255) / 256, 256, 0, stream>>>(W[l], Wp[l], dims[l], dims[l + 1]);
    }

    int gx = (NN + 127) / 128;  // 782

    // ---- layer 0: mgemm(x16,Wp0)->Hh(dis-scaled fp16); agg->bufA(+b0); BN->act16
    {
        dim3 grid(gx, 128 / 64);
        k_mgemm<4, true><<<grid, 256, 0, stream>>>(x16, Wp[0], Hh, NN, 128, 128, dis, nullptr);
        launch_agg_f(128, Hh, bufA, rowptr, degcnt, colv, dis, bp[0], stream);
        run_bn(bufA, act16, 128, gp[0], bep[0], bn, bnAB, stream);
    }
    // ---- layer 1 (agg first): scale16(act16)->Hh; agg->act16 fp16; mgemm+b1->bufA; BN->act16
    {
        k_scale16<<<(NN * 16 + 255) / 256, 256, 0, stream>>>(
            (const uint4*)act16, dis, (uint4*)Hh);
        constexpr int TPN = 16, G = 256 / TPN;
        k_agg_h<TPN, true><<<(NN + G - 1) / G, 256, 0, stream>>>(
            (const uint4*)Hh, act16, rowptr, degcnt, colv, dis, nullptr);
        dim3 grid(gx, 256 / 64);
        k_mgemm<4, false><<<grid, 256, 0, stream>>>(act16, Wp[1], bufA, NN, 128, 256, nullptr, bp[1]);
        run_bn(bufA, act16, 256, gp[1], bep[1], bn, bnAB, stream);
    }
    // ---- layer 2: mgemm(act16,Wp2)->Hh; agg->bufA(+b2); BN->act16
    {
        dim3 grid(gx, 128 / 64);
        k_mgemm<4, true><<<grid, 256, 0, stream>>>(act16, Wp[2], Hh, NN, 256, 128, dis, nullptr);
        launch_agg_f(128, Hh, bufA, rowptr, degcnt, colv, dis, bp[2], stream);
        run_bn(bufA, act16, 128, gp[2], bep[2], bn, bnAB, stream);
    }
    // ---- layer 3: mgemm(act16,Wp3)->Hh; agg->bufA(+b3); BN->act16
    {
        dim3 grid(gx, 64 / 64);
        k_mgemm<4, true><<<grid, 256, 0, stream>>>(act16, Wp[3], Hh, NN, 128, 64, dis, nullptr);
        launch_agg_f(64, Hh, bufA, rowptr, degcnt, colv, dis, bp[3], stream);
        run_bn(bufA, act16, 64, gp[3], bep[3], bn, bnAB, stream);
    }
    // ---- layer 4: mgemm(act16,Wp4)->Hh; agg->bufA(+b4); BN->act16
    {
        dim3 grid(gx, 1);
        k_mgemm<2, true><<<grid, 256, 0, stream>>>(act16, Wp[4], Hh, NN, 64, 32, dis, nullptr);
        launch_agg_f(32, Hh, bufA, rowptr, degcnt, colv, dis, bp[4], stream);
        run_bn(bufA, act16, 32, gp[4], bep[4], bn, bnAB, stream);
    }

    size_t edgeThreads = (size_t)EE * 4;
    k_edge16<<<(unsigned)((edgeThreads + 255) / 256), 256, 0, stream>>>(
        (const uint4*)act16, srcv, dstv, fcw, fcb, (float*)d_out);
}